// Round 5
// baseline (127.001 us; speedup 1.0000x reference)
//
#include <hip/hip_runtime.h>

#define B_      2
#define C_      256
#define H_      96
#define W_      96
#define HW_     (H_ * W_)
#define P_      7
#define PP_     (P_ * P_)
#define NROIS_  512
#define SCALE_  0.0625f
#define TSTD_   0.1f

#define NGROUP_ 8                       // channel groups
#define GC_     (C_ / NGROUP_)          // 32 channels per group

// LDS patch window: up to PATCH_MAX pixels; each pixel = 32 bf16 ch in
// 16 words + 4 pad words (PXSTRIDE=20 words = 80 B).  80-B px stride ->
// ds_read_b128 is 16-B aligned, and bank index (20*px + 4*chq) mod 32
// cycles through 8 distinct bases (period 8 in px) -> ~2-way conflicts.
#define PATCH_MAX 400
#define PXSTRIDE  20

typedef float vf4 __attribute__((ext_vector_type(4)));

// f32 -> bf16 (round-to-nearest-even), as raw bits
__device__ __forceinline__ unsigned f2bf(float f) {
    union { float f; unsigned u; } x; x.f = f;
    return (x.u + 0x7fffu + ((x.u >> 16) & 1u)) >> 16;
}
__device__ __forceinline__ float bf_lo(unsigned u) {
    union { unsigned i; float f; } x; x.i = u << 16; return x.f;
}
__device__ __forceinline__ float bf_hi(unsigned u) {
    union { unsigned i; float f; } x; x.i = u & 0xffff0000u; return x.f;
}

// ---------------------------------------------------------------------------
// Pass 1 (unchanged R6): f32 CHW -> bf16 group-planar [b][g][HW][32ch].
// ---------------------------------------------------------------------------
__global__ __launch_bounds__(256) void nchw_to_gp_bf16(const float* __restrict__ in,
                                                       ushort* __restrict__ out) {
    __shared__ float tile[32][36];          // [ch][px], stride 36: b128-aligned
    const int b   = blockIdx.z;
    const int g   = blockIdx.x & (NGROUP_ - 1);
    const int p0  = (blockIdx.x >> 3) * 32; // pixel tile origin
    const int c0  = g * 32;                 // channel tile origin
    const int tid = threadIdx.x;

    const float* src = in + (size_t)b * (C_ * HW_);
    ushort*      dst = out + ((size_t)(b * NGROUP_ + g) * HW_) * GC_;

    {
        const int cr = tid >> 3;            // 0..31 channel row
        const int pq = (tid & 7) * 4;       // pixel quad
        const vf4 v = __builtin_nontemporal_load(
            (const vf4*)&src[(size_t)(c0 + cr) * HW_ + p0 + pq]);
        *(vf4*)&tile[cr][pq] = v;
    }
    __syncthreads();
    {
        const int p  = tid >> 3;            // 0..31 pixel
        const int cq = (tid & 7) * 4;       // channel quad
        uint2 o;
        o.x = f2bf(tile[cq + 0][p]) | (f2bf(tile[cq + 1][p]) << 16);
        o.y = f2bf(tile[cq + 2][p]) | (f2bf(tile[cq + 3][p]) << 16);
        *(uint2*)&((unsigned*)dst)[(size_t)(p0 + p) * (GC_ / 2) + (cq >> 1)] = o;
    }
}

// ---------------------------------------------------------------------------
// Pass 2 (R11): LDS-patch taps, R8's traps fixed.
// Model (R7/R9/R10 eliminations): pass 2 is bound by per-CU service rate of
// scattered 64-B segments (784/block).  Staging the bbox patch from gp is
// 361 CONTIGUOUS segments/block (2.2x fewer, TA-pipelined); taps then read
// LDS (205 MB aggregate ~ 3 us at LDS BW) and the kernel goes VALU-bound.
// Fixes vs R8 (65 us): 32 KB patch (bf16, 80 B/px) -> 4 blocks/CU (was 2);
// no runtime division in staging (pow2-padded column, shift/mask); stripe
// loop with 1-row overlap replaces the use_patch fallback (uniform path,
// block-uniform trip count -> barriers legal).
// ---------------------------------------------------------------------------
__global__ __launch_bounds__(256, 4) void dpsroi_pool7(const ushort* __restrict__ feat,
                                                       const float* __restrict__ rois,
                                                       const float* __restrict__ trans,
                                                       float* __restrict__ out) {
    __shared__ __align__(16) unsigned patch[PATCH_MAX * PXSTRIDE];  // 32,000 B
    __shared__ float sout[GC_ * PP_];       // 6,272 B, global layout
    __shared__ float ttab[2 * PP_];
    __shared__ int   bb[4];                 // xmin, xmax, ymin, ymax

    const int blk = blockIdx.x;
    const int g   = blk & (NGROUP_ - 1);    // static XCD affinity
    const int n   = blk >> 3;
    const int tid = threadIdx.x;
    const int bin = tid >> 2;               // 0..63 (49 active)
    const int chq = tid & 3;
    const int ch0 = chq * 8;                // 8 channels per lane

    if (tid < 2 * PP_) ttab[tid] = trans[n * (2 * PP_) + tid];
    if (tid == 0) { bb[0] = 1 << 30; bb[1] = -(1 << 30); bb[2] = 1 << 30; bb[3] = -(1 << 30); }

    // ROI geometry (block-uniform)
    const int   broi = (int)rois[n * 5 + 0];
    const float x1 = rintf(rois[n * 5 + 1]) * SCALE_ - 0.5f;
    const float y1 = rintf(rois[n * 5 + 2]) * SCALE_ - 0.5f;
    const float x2 = (rintf(rois[n * 5 + 3]) + 1.0f) * SCALE_ - 0.5f;
    const float y2 = (rintf(rois[n * 5 + 4]) + 1.0f) * SCALE_ - 0.5f;
    const float rw = fmaxf(x2 - x1, 0.1f);
    const float rh = fmaxf(y2 - y1, 0.1f);
    const float bin_w = rw * (1.0f / 7.0f);
    const float bin_h = rh * (1.0f / 7.0f);
    const float sub_w = bin_w * 0.5f;
    const float sub_h = bin_h * 0.5f;

    __syncthreads();                        // ttab + bb init ready

    // ---- per-bin sample geometry + bbox contribution ----
    float wt[16];
    int   xs0[4], xs1[4], ys0[4], ys1[4];
    int   cnt = 0;
    if (bin < PP_) {
        const int pi = bin / P_;
        const int pj = bin - pi * P_;
        const float tx = ttab[bin] * TSTD_;
        const float ty = ttab[PP_ + bin] * TSTD_;
        const float wstart = (float)pj * bin_w + x1 + tx * rw;
        const float hstart = (float)pi * bin_h + y1 + ty * rh;

        if (chq == 0) {
            const int xlo = (int)floorf(fminf(fmaxf(wstart, 0.0f), (float)(W_ - 1)));
            const int xhi = (int)ceilf (fminf(fmaxf(wstart + sub_w, 0.0f), (float)(W_ - 1)));
            const int ylo = (int)floorf(fminf(fmaxf(hstart, 0.0f), (float)(H_ - 1)));
            const int yhi = (int)ceilf (fminf(fmaxf(hstart + sub_h, 0.0f), (float)(H_ - 1)));
            atomicMin(&bb[0], xlo); atomicMax(&bb[1], xhi);
            atomicMin(&bb[2], ylo); atomicMax(&bb[3], yhi);
        }

#pragma unroll
        for (int s = 0; s < 4; ++s) {
            const float w = wstart + (float)(s & 1) * sub_w;
            const float h = hstart + (float)(s >> 1) * sub_h;
            const bool valid = (w >= -0.5f) & (w <= (float)W_ - 0.5f) &
                               (h >= -0.5f) & (h <= (float)H_ - 0.5f);
            cnt += valid ? 1 : 0;
            const float vf = valid ? 1.0f : 0.0f;
            const float wc  = fminf(fmaxf(w, 0.0f), (float)(W_ - 1));
            const float hc  = fminf(fmaxf(h, 0.0f), (float)(H_ - 1));
            const float x0f = floorf(wc), y0f = floorf(hc);
            const float dx  = wc - x0f,   dy  = hc - y0f;
            xs0[s] = (int)x0f;           ys0[s] = (int)y0f;
            xs1[s] = (int)ceilf(wc);     ys1[s] = (int)ceilf(hc);
            wt[4 * s + 0] = vf * (1.0f - dx) * (1.0f - dy);
            wt[4 * s + 1] = vf * dx * (1.0f - dy);
            wt[4 * s + 2] = vf * (1.0f - dx) * dy;
            wt[4 * s + 3] = vf * dx * dy;
        }
    }
    __syncthreads();                        // bbox final

    const int bx0 = bb[0], by0 = bb[2];
    const int pw  = bb[1] - bb[0] + 1;      // <= ~60 for this data
    const int ph  = bb[3] - bb[2] + 1;
    const int mrows = PATCH_MAX / pw;       // rows per stripe (>= 4)
    const int nst   = (ph - 1) / (mrows - 1) + 1;

    // stripe assignment per sample (4 int divs, one-time)
    int ks[4] = {0, 0, 0, 0};
    if (bin < PP_) {
#pragma unroll
        for (int s = 0; s < 4; ++s) ks[s] = (ys0[s] - by0) / (mrows - 1);
    }

    const int pw4 = pw * 4;                 // uint4s per row
    int colpad = 128; while (colpad < pw4) colpad <<= 1;
    const int csh = __builtin_ctz(colpad);

    const uint4* fb4 = (const uint4*)(feat + ((size_t)(broi * NGROUP_ + g) * HW_) * GC_);

    float acc[8] = {0.f, 0.f, 0.f, 0.f, 0.f, 0.f, 0.f, 0.f};

    for (int k = 0; k < nst; ++k) {
        const int ys    = by0 + k * (mrows - 1);
        const int rem   = by0 + ph - ys;
        const int srows = (mrows < rem) ? mrows : rem;

        // ---- stage stripe rows [ys, ys+srows), coalesced from gp ----
        for (int t = tid; t < (srows << csh); t += 256) {
            const int r  = t >> csh;
            const int c4 = t & (colpad - 1);
            if (c4 < pw4) {
                const int px = r * pw + (c4 >> 2);
                *(uint4*)&patch[px * PXSTRIDE + (c4 & 3) * 4] =
                    fb4[((size_t)(ys + r) * W_ + bx0) * 4 + c4];
            }
        }
        __syncthreads();                    // stripe staged

        // ---- taps for samples assigned to this stripe ----
        if (bin < PP_) {
            const unsigned* pbase = patch + chq * 4;
#pragma unroll
            for (int s = 0; s < 4; ++s) {
                if (ks[s] == k) {
                    const int ry0 = ys0[s] - ys, ry1 = ys1[s] - ys;
                    const int cx0 = xs0[s] - bx0, cx1 = xs1[s] - bx0;
                    const uint4 v00 = *(const uint4*)&pbase[(ry0 * pw + cx0) * PXSTRIDE];
                    const uint4 v01 = *(const uint4*)&pbase[(ry0 * pw + cx1) * PXSTRIDE];
                    const uint4 v10 = *(const uint4*)&pbase[(ry1 * pw + cx0) * PXSTRIDE];
                    const uint4 v11 = *(const uint4*)&pbase[(ry1 * pw + cx1) * PXSTRIDE];
                    const float w00 = wt[4 * s + 0], w01 = wt[4 * s + 1];
                    const float w10 = wt[4 * s + 2], w11 = wt[4 * s + 3];
                    acc[0] += w00 * bf_lo(v00.x) + w01 * bf_lo(v01.x) + w10 * bf_lo(v10.x) + w11 * bf_lo(v11.x);
                    acc[1] += w00 * bf_hi(v00.x) + w01 * bf_hi(v01.x) + w10 * bf_hi(v10.x) + w11 * bf_hi(v11.x);
                    acc[2] += w00 * bf_lo(v00.y) + w01 * bf_lo(v01.y) + w10 * bf_lo(v10.y) + w11 * bf_lo(v11.y);
                    acc[3] += w00 * bf_hi(v00.y) + w01 * bf_hi(v01.y) + w10 * bf_hi(v10.y) + w11 * bf_hi(v11.y);
                    acc[4] += w00 * bf_lo(v00.z) + w01 * bf_lo(v01.z) + w10 * bf_lo(v10.z) + w11 * bf_lo(v11.z);
                    acc[5] += w00 * bf_hi(v00.z) + w01 * bf_hi(v01.z) + w10 * bf_hi(v10.z) + w11 * bf_hi(v11.z);
                    acc[6] += w00 * bf_lo(v00.w) + w01 * bf_lo(v01.w) + w10 * bf_lo(v10.w) + w11 * bf_lo(v11.w);
                    acc[7] += w00 * bf_hi(v00.w) + w01 * bf_hi(v01.w) + w10 * bf_hi(v10.w) + w11 * bf_hi(v11.w);
                }
            }
        }
        __syncthreads();                    // tap reads done before restage
    }

    if (bin < PP_) {
        const float inv = (cnt > 0) ? (1.0f / (float)cnt) : 0.0f;
#pragma unroll
        for (int j = 0; j < 8; ++j)
            sout[(ch0 + j) * PP_ + bin] = acc[j] * inv;
    }

    __syncthreads();
    // out[n, g*32 : (g+1)*32, :, :] contiguous: 32*49 = 1568 floats
    float* outn = out + ((size_t)n * C_ + g * GC_) * PP_;
    for (int f = tid; f < GC_ * PP_; f += 256)
        __builtin_nontemporal_store(sout[f], &outn[f]);
}

extern "C" void kernel_launch(void* const* d_in, const int* in_sizes, int n_in,
                              void* d_out, int out_size, void* d_ws, size_t ws_size,
                              hipStream_t stream) {
    const float* feat  = (const float*)d_in[0];   // (2,256,96,96) f32
    const float* rois  = (const float*)d_in[1];   // (512,5)
    const float* trans = (const float*)d_in[2];   // (512,2,7,7)
    float* out = (float*)d_out;                   // (512,256,7,7) f32

    ushort* gp = (ushort*)d_ws;                   // bf16 group-planar, 9.4 MB
    dim3 tb(256);
    dim3 tg((HW_ / 32) * NGROUP_, 1, B_);         // g = blockIdx.x & 7
    nchw_to_gp_bf16<<<tg, tb, 0, stream>>>(feat, gp);
    dpsroi_pool7<<<NROIS_ * NGROUP_, 256, 0, stream>>>(gp, rois, trans, out);
}

// Round 6
// 89.382 us; speedup vs baseline: 1.4209x; 1.4209x over previous
//
#include <hip/hip_runtime.h>

#define B_      2
#define C_      256
#define H_      96
#define W_      96
#define HW_     (H_ * W_)
#define P_      7
#define PP_     (P_ * P_)
#define NROIS_  512
#define SCALE_  0.0625f
#define TSTD_   0.1f

#define NGROUP_ 8                       // channel groups
#define GC_     (C_ / NGROUP_)          // 32 channels per group

typedef float vf4 __attribute__((ext_vector_type(4)));   // native vec for nt builtins

// f32 -> bf16 (round-to-nearest-even), as raw bits
__device__ __forceinline__ unsigned f2bf(float f) {
    union { float f; unsigned u; } x; x.f = f;
    return (x.u + 0x7fffu + ((x.u >> 16) & 1u)) >> 16;
}
__device__ __forceinline__ float bf_lo(unsigned u) {
    union { unsigned i; float f; } x; x.i = u << 16; return x.f;
}
__device__ __forceinline__ float bf_hi(unsigned u) {
    union { unsigned i; float f; } x; x.i = u & 0xffff0000u; return x.f;
}

// ---------------------------------------------------------------------------
// Pass 1: f32 CHW -> bf16 group-planar [b][g][HW][32ch].
// Read: ONE vf4 pass (32ch x 32px per block, 128 B segments / 8 lanes).
// Tile row stride 36 floats -> 16B-aligned vector LDS writes.
// Write: one pass, uint2 (4 packed bf16) per lane, coalesced.
// ---------------------------------------------------------------------------
__global__ __launch_bounds__(256) void nchw_to_gp_bf16(const float* __restrict__ in,
                                                       ushort* __restrict__ out) {
    __shared__ float tile[32][36];          // [ch][px], stride 36: b128-aligned
    const int b   = blockIdx.z;
    const int g   = blockIdx.x & (NGROUP_ - 1);
    const int p0  = (blockIdx.x >> 3) * 32; // pixel tile origin
    const int c0  = g * 32;                 // channel tile origin
    const int tid = threadIdx.x;

    const float* src = in + (size_t)b * (C_ * HW_);
    ushort*      dst = out + ((size_t)(b * NGROUP_ + g) * HW_) * GC_;

    // read: lane = (ch row, px quad); one vf4 per thread covers 32x32
    {
        const int cr = tid >> 3;            // 0..31 channel row
        const int pq = (tid & 7) * 4;       // pixel quad
        const vf4 v = __builtin_nontemporal_load(
            (const vf4*)&src[(size_t)(c0 + cr) * HW_ + p0 + pq]);
        *(vf4*)&tile[cr][pq] = v;
    }
    __syncthreads();

    // write: lane = (px, ch quad); pack 4 ch -> uint2, coalesced
    {
        const int p  = tid >> 3;            // 0..31 pixel
        const int cq = (tid & 7) * 4;       // channel quad
        uint2 o;
        o.x = f2bf(tile[cq + 0][p]) | (f2bf(tile[cq + 1][p]) << 16);
        o.y = f2bf(tile[cq + 2][p]) | (f2bf(tile[cq + 3][p]) << 16);
        *(uint2*)&((unsigned*)dst)[(size_t)(p0 + p) * (GC_ / 2) + (cq >> 1)] = o;
    }
}

// ---------------------------------------------------------------------------
// Pass 2 (R12 = R0 revert + float4 epilogue): block = (roi n, group g),
// g = blockIdx.x & 7 (static XCD affinity).  4 lanes/bin x uint4 (8 bf16 ch)
// = 64 B line per corner; all 16 gathers hoisted in flight.
// Model (closed over R7-R11): this kernel moves 205 MB of tap data through
// the per-CU VMEM path at ~5.4 TB/s = 86% of the 6.3 TB/s copy ceiling.
// Byte-count is invariant to instruction shape (R7 null), occupancy (R10
// null), and is only beaten by staging schemes whose overheads exceed their
// 1.25x byte win (R8/R11 regressions).  This structure is the measured best.
// __launch_bounds__(256,4): the v[16]+wt+ofs register set sits at the
// 128-VGPR occupancy cliff; creep past it halves outstanding lines.
// ---------------------------------------------------------------------------
__global__ __launch_bounds__(256, 4) void dpsroi_pool7(const ushort* __restrict__ feat,
                                                       const float* __restrict__ rois,
                                                       const float* __restrict__ trans,
                                                       float* __restrict__ out) {
    __shared__ __align__(16) float sout[GC_ * PP_];   // 32*49*4 = 6272 B, global layout

    const int blk = blockIdx.x;
    const int g   = blk & (NGROUP_ - 1);
    const int n   = blk >> 3;
    const int tid = threadIdx.x;
    const int bin = tid >> 2;               // 0..63 (49 active)
    const int ch0 = (tid & 3) * 8;          // 8 channels per lane

    // ROI geometry (block-uniform)
    const int   broi = (int)rois[n * 5 + 0];
    const float x1 = rintf(rois[n * 5 + 1]) * SCALE_ - 0.5f;
    const float y1 = rintf(rois[n * 5 + 2]) * SCALE_ - 0.5f;
    const float x2 = (rintf(rois[n * 5 + 3]) + 1.0f) * SCALE_ - 0.5f;
    const float y2 = (rintf(rois[n * 5 + 4]) + 1.0f) * SCALE_ - 0.5f;
    const float rw = fmaxf(x2 - x1, 0.1f);
    const float rh = fmaxf(y2 - y1, 0.1f);
    const float bin_w = rw * (1.0f / 7.0f);
    const float bin_h = rh * (1.0f / 7.0f);
    const float sub_w = bin_w * 0.5f;
    const float sub_h = bin_h * 0.5f;

    const ushort* fb = feat + ((size_t)(broi * NGROUP_ + g) * HW_) * GC_ + ch0;

    if (bin < PP_) {
        const int pi = bin / P_;
        const int pj = bin - pi * P_;
        const float tx = trans[((n * 2 + 0) * P_ + pi) * P_ + pj] * TSTD_;
        const float ty = trans[((n * 2 + 1) * P_ + pi) * P_ + pj] * TSTD_;
        const float wstart = (float)pj * bin_w + x1 + tx * rw;
        const float hstart = (float)pi * bin_h + y1 + ty * rh;

        // ---- phase 1: all 16 weights + offsets ----
        float wt[16];
        int   ofs[16];
        int   cnt = 0;
#pragma unroll
        for (int s = 0; s < 4; ++s) {
            const float w = wstart + (float)(s & 1) * sub_w;
            const float h = hstart + (float)(s >> 1) * sub_h;
            const bool valid = (w >= -0.5f) & (w <= (float)W_ - 0.5f) &
                               (h >= -0.5f) & (h <= (float)H_ - 0.5f);
            cnt += valid ? 1 : 0;
            const float vf = valid ? 1.0f : 0.0f;
            const float wc  = fminf(fmaxf(w, 0.0f), (float)(W_ - 1));
            const float hc  = fminf(fmaxf(h, 0.0f), (float)(H_ - 1));
            const float x0f = floorf(wc), y0f = floorf(hc);
            const float dx  = wc - x0f,   dy  = hc - y0f;
            const int   x0  = (int)x0f,   y0  = (int)y0f;
            const int   xp  = (int)ceilf(wc), yp = (int)ceilf(hc);
            wt[4 * s + 0] = vf * (1.0f - dx) * (1.0f - dy);
            wt[4 * s + 1] = vf * dx * (1.0f - dy);
            wt[4 * s + 2] = vf * (1.0f - dx) * dy;
            wt[4 * s + 3] = vf * dx * dy;
            ofs[4 * s + 0] = y0 * W_ + x0;
            ofs[4 * s + 1] = y0 * W_ + xp;
            ofs[4 * s + 2] = yp * W_ + x0;
            ofs[4 * s + 3] = yp * W_ + xp;
        }

        // ---- phase 2: ALL 16 gathers in flight ----
        uint4 v[16];
#pragma unroll
        for (int i = 0; i < 16; ++i)
            v[i] = *(const uint4*)(fb + (size_t)ofs[i] * GC_);

        // ---- phase 3: unpack + FMA in load order ----
        float acc[8] = {0.f, 0.f, 0.f, 0.f, 0.f, 0.f, 0.f, 0.f};
#pragma unroll
        for (int i = 0; i < 16; ++i) {
            const float wgt = wt[i];
            acc[0] += wgt * bf_lo(v[i].x);
            acc[1] += wgt * bf_hi(v[i].x);
            acc[2] += wgt * bf_lo(v[i].y);
            acc[3] += wgt * bf_hi(v[i].y);
            acc[4] += wgt * bf_lo(v[i].z);
            acc[5] += wgt * bf_hi(v[i].z);
            acc[6] += wgt * bf_lo(v[i].w);
            acc[7] += wgt * bf_hi(v[i].w);
        }

        const float inv = (cnt > 0) ? (1.0f / (float)cnt) : 0.0f;
#pragma unroll
        for (int j = 0; j < 8; ++j)
            sout[(ch0 + j) * PP_ + bin] = acc[j] * inv;
    }

    __syncthreads();
    // out[n, g*32 : (g+1)*32, :, :] contiguous: 1568 floats = 392 float4
    float* outn = out + ((size_t)n * C_ + g * GC_) * PP_;
    const vf4* s4 = (const vf4*)sout;
    for (int f = tid; f < (GC_ * PP_) / 4; f += 256)
        __builtin_nontemporal_store(s4[f], &((vf4*)outn)[f]);
}

extern "C" void kernel_launch(void* const* d_in, const int* in_sizes, int n_in,
                              void* d_out, int out_size, void* d_ws, size_t ws_size,
                              hipStream_t stream) {
    const float* feat  = (const float*)d_in[0];   // (2,256,96,96) f32
    const float* rois  = (const float*)d_in[1];   // (512,5)
    const float* trans = (const float*)d_in[2];   // (512,2,7,7)
    float* out = (float*)d_out;                   // (512,256,7,7) f32

    ushort* gp = (ushort*)d_ws;                   // bf16 group-planar, 9.4 MB
    dim3 tb(256);
    dim3 tg((HW_ / 32) * NGROUP_, 1, B_);         // g = blockIdx.x & 7
    nchw_to_gp_bf16<<<tg, tb, 0, stream>>>(feat, gp);
    dpsroi_pool7<<<NROIS_ * NGROUP_, 256, 0, stream>>>(gp, rois, trans, out);
}